// Round 5
// baseline (163.668 us; speedup 1.0000x reference)
//
#include <hip/hip_runtime.h>
#include <stdint.h>

#define N 4096
#define B 2
#define D 128
#define LOG2E 1.4426950408889634f

__device__ __forceinline__ float lrelu(float t) { return t > 0.f ? t : 0.01f * t; }

// K12: merged u-vector + row kernel. Each block (4 rows) redundantly computes
// u_l = Wa^T w_l, u_r = Wa^T w_r into LDS (Wa is 64KB, L2-resident; w_l[e] is
// wave-uniform -> scalar loads), then does the 3 per-row dot products.
__global__ __launch_bounds__(256) void k12_rows(
    const float* __restrict__ x,     // [B*N, D]
    const float* __restrict__ Wd,    // [D]
    const float* __restrict__ bd,    // [1]
    const float* __restrict__ Wa,    // [D, D]
    const float* __restrict__ w_l,   // [D]
    const float* __restrict__ w_r,   // [D]
    float* __restrict__ out_dem,     // [B*N] (start of d_out)
    float* __restrict__ lv,
    float* __restrict__ rv) {
    __shared__ float su[256];        // u_l[0..127], u_r[128..255]
    __shared__ float2 pl[4][64];
    __shared__ float2 pr[4][64];
    int t = threadIdx.x;
    int d2 = t & 63;
    int h = t >> 6;
    const float2* Wa2 = (const float2*)Wa;
    float2 al = make_float2(0.f, 0.f), ar = make_float2(0.f, 0.f);
    #pragma unroll 8
    for (int k = 0; k < 32; ++k) {
        int e = h * 32 + k;          // wave-uniform
        float2 w = Wa2[e * 64 + d2]; // Wa[e, 2*d2], Wa[e, 2*d2+1]
        float wlv = w_l[e];          // scalar load (uniform)
        float wrv = w_r[e];
        al.x += w.x * wlv; al.y += w.y * wlv;
        ar.x += w.x * wrv; ar.y += w.y * wrv;
    }
    pl[h][d2] = al; pr[h][d2] = ar;
    __syncthreads();
    if (t < 64) {
        float2 s = make_float2(0.f, 0.f);
        #pragma unroll
        for (int hh = 0; hh < 4; ++hh) { s.x += pl[hh][t].x; s.y += pl[hh][t].y; }
        ((float2*)su)[t] = s;
    } else if (t < 128) {
        int dd = t - 64;
        float2 s = make_float2(0.f, 0.f);
        #pragma unroll
        for (int hh = 0; hh < 4; ++hh) { s.x += pr[hh][dd].x; s.y += pr[hh][dd].y; }
        ((float2*)(su + 128))[dd] = s;
    }
    __syncthreads();

    // row phase: one wave per row, lane handles d = 2*lane, 2*lane+1
    int lane = t & 63;
    int row = blockIdx.x * 4 + (t >> 6);
    float2 xv = ((const float2*)(x + (size_t)row * D))[lane];
    float2 ul2 = ((const float2*)su)[lane];
    float2 ur2 = ((const float2*)(su + 128))[lane];
    float2 wv = ((const float2*)Wd)[lane];
    float pl_ = xv.x * ul2.x + xv.y * ul2.y;
    float pr_ = xv.x * ur2.x + xv.y * ur2.y;
    float pd_ = xv.x * wv.x + xv.y * wv.y;
    #pragma unroll
    for (int m = 32; m >= 1; m >>= 1) {
        pl_ += __shfl_xor(pl_, m, 64);
        pr_ += __shfl_xor(pr_, m, 64);
        pd_ += __shfl_xor(pd_, m, 64);
    }
    if (lane == 0) {
        float dem = 1.f / (1.f + __expf(-(pd_ + bd[0])));
        out_dem[row] = dem;
        lv[row] = pl_ * LOG2E;   // exp2 domain (lrelu commutes with positive scale)
        rv[row] = pr_ * LOG2E;
    }
}

// K3: 4 rows per block (same b). Stage r in LDS; rmax; denom; coalesced write.
// ROWS=4 -> 2048 blocks = 8 blocks/CU = 32 waves/CU (max occupancy) — R2 best.
__global__ __launch_bounds__(256) void k3_main(
    const float* __restrict__ lv, const float* __restrict__ rv,
    const float* __restrict__ dem_f,      // demands (fp32, start of d_out)
    float* __restrict__ out_g) {          // [B,N,N] fp32
    __shared__ float sr[N];
    __shared__ float redmax[4];
    __shared__ float redsum[4][4];
    int tid = threadIdx.x;
    int b = blockIdx.x >> 10;             // /1024 blocks-per-b
    int i0 = (blockIdx.x & 1023) << 2;    // *4 rows
    const float* rb = rv + b * N;
    float lmax = -3.402823466e38f;
    #pragma unroll
    for (int k = 0; k < N / 256; ++k) {
        float v = rb[tid + k * 256];
        sr[tid + k * 256] = v;            // stride-256: 2 lanes/bank -> free
        lmax = fmaxf(lmax, v);
    }
    #pragma unroll
    for (int m = 32; m >= 1; m >>= 1) lmax = fmaxf(lmax, __shfl_xor(lmax, m, 64));
    if ((tid & 63) == 0) redmax[tid >> 6] = lmax;
    __syncthreads();
    float rmax = fmaxf(fmaxf(redmax[0], redmax[1]), fmaxf(redmax[2], redmax[3]));

    int rowbase = b * N + i0;
    float lr_[4], mr[4], s[4];
    #pragma unroll
    for (int q = 0; q < 4; ++q) {
        lr_[q] = lv[rowbase + q];
        mr[q] = lrelu(lr_[q] + rmax);     // true row max (lrelu monotone)
        s[q] = 0.f;
    }
    #pragma unroll 2
    for (int k = 0; k < N / 256; ++k) {
        float r = sr[tid + k * 256];
        #pragma unroll
        for (int q = 0; q < 4; ++q) s[q] += exp2f(lrelu(lr_[q] + r) - mr[q]);
    }
    #pragma unroll
    for (int m = 32; m >= 1; m >>= 1) {
        #pragma unroll
        for (int q = 0; q < 4; ++q) s[q] += __shfl_xor(s[q], m, 64);
    }
    if ((tid & 63) == 0) {
        #pragma unroll
        for (int q = 0; q < 4; ++q) redsum[tid >> 6][q] = s[q];
    }
    __syncthreads();
    float sc[4];
    #pragma unroll
    for (int q = 0; q < 4; ++q) {
        float den = redsum[0][q] + redsum[1][q] + redsum[2][q] + redsum[3][q];
        sc[q] = dem_f[rowbase + q] / den;
    }
    // Write pass: each thread owns one float4 (j = idx*4..idx*4+3) per row ->
    // lane i stores at base+16*i, perfectly coalesced. r re-read from global
    // (L1/L2-hot).
    const float4* rb4 = (const float4*)rb;
    size_t gbase = (size_t)b * N * N + (size_t)i0 * N;
    #pragma unroll
    for (int it = 0; it < 4; ++it) {
        int idx = it * 256 + tid;          // 0..1023, j0 = idx*4
        float4 r4 = rb4[idx];
        #pragma unroll
        for (int q = 0; q < 4; ++q) {
            float4 o;
            o.x = exp2f(lrelu(lr_[q] + r4.x) - mr[q]) * sc[q];
            o.y = exp2f(lrelu(lr_[q] + r4.y) - mr[q]) * sc[q];
            o.z = exp2f(lrelu(lr_[q] + r4.z) - mr[q]) * sc[q];
            o.w = exp2f(lrelu(lr_[q] + r4.w) - mr[q]) * sc[q];
            *(float4*)(out_g + gbase + (size_t)q * N + (size_t)idx * 4) = o;
        }
    }
}

extern "C" void kernel_launch(void* const* d_in, const int* in_sizes, int n_in,
                              void* d_out, int out_size, void* d_ws, size_t ws_size,
                              hipStream_t stream) {
    const float* x  = (const float*)d_in[0];
    const float* Wd = (const float*)d_in[2];
    const float* bd = (const float*)d_in[3];
    const float* Wa = (const float*)d_in[4];
    const float* wl = (const float*)d_in[5];
    const float* wr = (const float*)d_in[6];

    float* ws = (float*)d_ws;
    float* lv = ws;                 // 8192
    float* rv = ws + 8192;          // 8192

    float* out     = (float*)d_out;
    float* out_dem = out;           // [B*N]
    float* out_g   = out + B * N;   // [B,N,N]

    hipLaunchKernelGGL(k12_rows, dim3(B * N / 4), dim3(256), 0, stream,
                       x, Wd, bd, Wa, wl, wr, out_dem, lv, rv);
    hipLaunchKernelGGL(k3_main, dim3(B * N / 4), dim3(256), 0, stream,
                       lv, rv, out_dem, out_g);
}